// Round 8
// baseline (1854.322 us; speedup 1.0000x reference)
//
#include <hip/hip_runtime.h>
#include <cfloat>
#include <climits>

// B=4, N_DAY=2048, N_CELLS=8192, D_MICRO=11, D=256, TOPK=32
static constexpr float SCALE = 0.0625f;  // 256^-0.5

// ---------------- kernel A: x_micro = micro @ mp_w + mp_b  → outX region ----
__global__ __launch_bounds__(256) void k_micro_mlp(
    const float* __restrict__ micro, const float* __restrict__ mpw,
    const float* __restrict__ mpb, float* __restrict__ xm) {
  const int r0 = blockIdx.x * 8;
  const int tid = threadIdx.x;
  __shared__ float ml[8][12];
  if (tid < 88) ml[tid / 11][tid % 11] = micro[(size_t)(r0 + tid / 11) * 11 + tid % 11];
  __syncthreads();
  const int d = tid;
  const float bias = mpb[d];
  float acc[8];
#pragma unroll
  for (int r = 0; r < 8; ++r) acc[r] = bias;
#pragma unroll
  for (int i = 0; i < 11; ++i) {
    const float w = mpw[i * 256 + d];
#pragma unroll
    for (int r = 0; r < 8; ++r) acc[r] = fmaf(ml[r][i], w, acc[r]);
  }
#pragma unroll
  for (int r = 0; r < 8; ++r) xm[(size_t)(r0 + r) * 256 + d] = acc[r];
}

// -------- kernel B: CT[256 x M] = (A[M x 256] @ W[256 x 256])^T -------------
// Same fmaf chain as the round-3/6 passing GEMM (k ascending; product operands
// merely commuted — exact). Only the OUTPUT indexing is transposed, written
// coalesced: thread covers 4 n-rows x 4 consecutive m-cols.
__global__ __launch_bounds__(256) void k_gemm256T(
    const float* __restrict__ A, const float* __restrict__ W,
    float* __restrict__ CT, int M) {
  const int bx = blockIdx.x;
  const int m0 = (bx >> 2) * 64, n0 = (bx & 3) * 64;
  const int tid = threadIdx.x;
  __shared__ __align__(16) float Al[16][72];  // k-major [k][m]
  __shared__ __align__(16) float Wl[16][72];  // k-major [k][n]
  float acc[4][4] = {};
  const int mg = tid >> 4, ng = tid & 15;
  for (int k0 = 0; k0 < 256; k0 += 16) {
    __syncthreads();
    {
      const int m = tid >> 2, ko = (tid & 3) << 2;
      const float4 a = *(const float4*)&A[(size_t)(m0 + m) * 256 + k0 + ko];
      Al[ko + 0][m] = a.x; Al[ko + 1][m] = a.y; Al[ko + 2][m] = a.z; Al[ko + 3][m] = a.w;
      const int kr = tid >> 4, no = (tid & 15) << 2;
      *(float4*)&Wl[kr][no] = *(const float4*)&W[(size_t)(k0 + kr) * 256 + n0 + no];
    }
    __syncthreads();
#pragma unroll
    for (int kk = 0; kk < 16; ++kk) {
      const float4 wv = *(const float4*)&Wl[kk][mg << 2];  // 4 n-values
      const float4 av = *(const float4*)&Al[kk][ng << 2];  // 4 m-values
      const float w_[4] = {wv.x, wv.y, wv.z, wv.w};
      const float a_[4] = {av.x, av.y, av.z, av.w};
#pragma unroll
      for (int i = 0; i < 4; ++i)
#pragma unroll
        for (int j = 0; j < 4; ++j) acc[i][j] = fmaf(w_[i], a_[j], acc[i][j]);
    }
  }
#pragma unroll
  for (int i = 0; i < 4; ++i) {
    float4 o = {acc[i][0], acc[i][1], acc[i][2], acc[i][3]};
    *(float4*)&CT[(size_t)(n0 + (mg << 2) + i) * M + m0 + (ng << 2)] = o;
  }
}

// ---------------- kernel C: LDS-free fp32 scores + online top-32 ------------
// BIT-IDENTITY: per score a single fp32 fmaf chain, k ascending 0..255, then
// *SCALE — identical to the round-3/6 passing arithmetic (Qt/Kt hold the same
// values; only memory layout changed). NO LDS: Kt rows load as perfectly
// coalesced float4 (lane-consecutive), Qt values are wave-uniform scalar
// loads feeding the SGPR operand of v_fma. Wave = 16 q x 256 c, acc[16][4].
// ROUND-8 FIX: qbase no longer double-counts the batch offset (r7 bug: qloc
// already contained bll*2048, shifting Q by one k-row for batches 1-3 →
// garbage indices with near-identical softmax weights).
__global__ __launch_bounds__(256, 2) void k_scores_topk(
    const float* __restrict__ Qt, const float* __restrict__ Kt,
    float* __restrict__ tkv, int* __restrict__ tki, int nbm, int lgnb) {
  const int b = blockIdx.x;
  const int part = b & 3;
  const int bll = (b >> 2) & nbm;
  const int qb = b >> (2 + lgnb);
  const int tid = threadIdx.x;
  const int w = tid >> 6;
  const int lane = tid & 63;
  const int qloc = bll * 2048 + qb * 64;          // GLOBAL query idx (store)
  const int wu = __builtin_amdgcn_readfirstlane(w);
  // per-batch block + within-batch column ONLY:
  const float* qbase = Qt + (size_t)bll * 524288 + qb * 64 + wu * 16;
  const float* kbase = Kt + (size_t)bll * 2097152;

  float lv[16];
  int li[16];
#pragma unroll
  for (int qi = 0; qi < 16; ++qi) { lv[qi] = -FLT_MAX; li[qi] = 0x7fffffff; }

#pragma unroll 1
  for (int ct = 0; ct < 8; ++ct) {
    const int c0 = part * 2048 + ct * 256;
    const float* kp = kbase + c0 + 4 * lane;
    float acc[16][4] = {};
#pragma unroll 4
    for (int kk = 0; kk < 256; ++kk) {
      const float4 kv = *(const float4*)(kp + (size_t)kk * 8192);
      const float* qrow = qbase + (size_t)kk * 2048;   // wave-uniform → s_load
#pragma unroll
      for (int qi = 0; qi < 16; ++qi) {
        const float sq = qrow[qi];
        acc[qi][0] = fmaf(sq, kv.x, acc[qi][0]);
        acc[qi][1] = fmaf(sq, kv.y, acc[qi][1]);
        acc[qi][2] = fmaf(sq, kv.z, acc[qi][2]);
        acc[qi][3] = fmaf(sq, kv.w, acc[qi][3]);
      }
    }
    // ---- selection: sorted 32-slot lane-list (lanes 0..31) per query.
    // Candidate order is NOT monotone in c → order-robust comparator:
    // accept if v > cm, or v == cm and idx < cm's idx (jax: value desc,
    // index asc). Insert position by ballot-prefix; list shifts down.
#pragma unroll
    for (int qi = 0; qi < 16; ++qi) {
#pragma unroll
      for (int j = 0; j < 4; ++j) {
        const float vj = acc[qi][j] * SCALE;
        const int cj = c0 + 4 * lane + j;
        float cmq = __shfl(lv[qi], 31);
        int cmi = __shfl(li[qi], 31);
        unsigned long long mask =
            __ballot(vj > cmq || (vj == cmq && cj < cmi));
        while (mask) {
          const int src = __ffsll(mask) - 1;
          mask &= mask - 1;
          const float cv = __shfl(vj, src);
          const int cidx = __shfl(cj, src);
          if (cv > cmq || (cv == cmq && cidx < cmi)) {  // wave-uniform
            const bool above = (lane < 32) &&
                (lv[qi] > cv || (lv[qi] == cv && li[qi] < cidx));
            const int p = __popcll(__ballot(above));
            const int pl = (lane == 0) ? 0 : lane - 1;
            const float pv = __shfl(lv[qi], pl);
            const int pi = __shfl(li[qi], pl);
            if (lane == p) { lv[qi] = cv; li[qi] = cidx; }
            else if (lane > p && lane < 32) { lv[qi] = pv; li[qi] = pi; }
            cmq = __shfl(lv[qi], 31);
            cmi = __shfl(li[qi], 31);
          }
        }
      }
    }
  }
#pragma unroll
  for (int qi = 0; qi < 16; ++qi) {
    if (lane < 32) {
      const size_t q = (size_t)(qloc + w * 16 + qi);
      tkv[q * 128 + part * 32 + lane] = lv[qi];
      tki[q * 128 + part * 32 + lane] = li[qi];
    }
  }
}

// ---------------- kernel D: merge parts, softmax, context, output proj ------
// context = (sum_k w_k * macro[i_k]) @ wv  (V never materialized)
__global__ __launch_bounds__(256) void k_finalize(
    const float* __restrict__ macro, const float* __restrict__ wv,
    const float* __restrict__ tkv, const int* __restrict__ tki,
    const float* __restrict__ opw, const float* __restrict__ opb,
    float* __restrict__ outX, float* __restrict__ outW, float* __restrict__ outI,
    int b0) {
  const int ql = blockIdx.x;
  const int bl = ql >> 11;
  const size_t gq = (size_t)b0 * 2048 + ql;
  const int tid = threadIdx.x;
  __shared__ float wts[32];
  __shared__ int sidx[32];
  __shared__ float mbar[256];
  __shared__ float ctx[256];
  if (tid < 32) { wts[tid] = 0.f; sidx[tid] = 0; }  // defensive
  __syncthreads();
  if (tid < 64) {
    const int lane = tid;
    float v0 = tkv[(size_t)ql * 128 + lane];
    int   i0 = tki[(size_t)ql * 128 + lane];
    float v1 = tkv[(size_t)ql * 128 + 64 + lane];
    int   i1 = tki[(size_t)ql * 128 + 64 + lane];
    int r0 = 0, r1 = 0;
#pragma unroll
    for (int j = 0; j < 64; ++j) {
      const float a0 = __shfl(v0, j); const int c0 = __shfl(i0, j);
      const float a1 = __shfl(v1, j); const int c1 = __shfl(i1, j);
      r0 += (a0 > v0 || (a0 == v0 && c0 < i0)) ? 1 : 0;
      r0 += (a1 > v0 || (a1 == v0 && c1 < i0)) ? 1 : 0;
      r1 += (a0 > v1 || (a0 == v1 && c0 < i1)) ? 1 : 0;
      r1 += (a1 > v1 || (a1 == v1 && c1 < i1)) ? 1 : 0;
    }
    float mv = fmaxf(v0, v1);
#pragma unroll
    for (int off = 32; off >= 1; off >>= 1) mv = fmaxf(mv, __shfl_xor(mv, off));
    const float e0 = (r0 < 32) ? expf(v0 - mv) : 0.f;
    const float e1 = (r1 < 32) ? expf(v1 - mv) : 0.f;
    float s = e0 + e1;
#pragma unroll
    for (int off = 32; off >= 1; off >>= 1) s += __shfl_xor(s, off);
    const float inv = 1.f / s;
    if (r0 < 32) {
      const float w_ = e0 * inv;
      wts[r0] = w_; sidx[r0] = i0;
      outW[gq * 32 + r0] = w_;
      outI[gq * 32 + r0] = (float)i0;
    }
    if (r1 < 32) {
      const float w_ = e1 * inv;
      wts[r1] = w_; sidx[r1] = i1;
      outW[gq * 32 + r1] = w_;
      outI[gq * 32 + r1] = (float)i1;
    }
  }
  __syncthreads();
  const int d = tid;
  float m = 0.f;
#pragma unroll 8
  for (int k = 0; k < 32; ++k) {
    const int si = sidx[k] & 8191;  // clamp: logic error → absmax, not fault
    m = fmaf(wts[k], macro[((size_t)bl * 8192 + si) * 256 + d], m);
  }
  mbar[d] = m;
  __syncthreads();
  float c = 0.f;
#pragma unroll 8
  for (int j = 0; j < 256; ++j) c = fmaf(mbar[j], wv[j * 256 + d], c);
  ctx[d] = c;
  __syncthreads();
  float y = outX[gq * 256 + d] + opb[d];  // xm stored in outX by kernel A
#pragma unroll 8
  for (int j = 0; j < 256; ++j) y = fmaf(ctx[j], opw[j * 256 + d], y);
  outX[gq * 256 + d] = y;
}

extern "C" void kernel_launch(void* const* d_in, const int* in_sizes, int n_in,
                              void* d_out, int out_size, void* d_ws, size_t ws_size,
                              hipStream_t stream) {
  const float* micro = (const float*)d_in[0];
  const float* macro = (const float*)d_in[1];
  const float* mpw   = (const float*)d_in[2];
  const float* mpb   = (const float*)d_in[3];
  const float* wq    = (const float*)d_in[4];
  const float* wk    = (const float*)d_in[5];
  const float* wv    = (const float*)d_in[6];
  const float* opw   = (const float*)d_in[7];
  const float* opb   = (const float*)d_in[8];

  float* outX = (float*)d_out;          // [4,2048,256]
  float* outW = outX + 2097152;         // [4,2048,32]
  float* outI = outX + 2359296;         // [4,2048,32] idx as float

  // Tiers (round-6 timing proves ws >= 50 MiB): Qt nb*2MB, Kt nb*8MB, cand 2MB*nb.
  int nb, lgnb;
  const size_t MB = 1024 * 1024;
  if (ws_size >= 50 * MB)      { nb = 4; lgnb = 2; }  // 48.4 MiB, grid 512
  else if (ws_size >= 26 * MB) { nb = 2; lgnb = 1; }  // 24.2 MiB
  else                         { nb = 1; lgnb = 0; }  // 12.1 MiB

  float* Qt  = (float*)d_ws;                         // [nb][256][2048]
  float* Kt  = Qt + (size_t)nb * 524288;             // [nb][256][8192]
  float* tkv = Kt + (size_t)nb * 2097152;
  int*   tki = (int*)(tkv + (size_t)nb * 2048 * 128);

  // x_micro for all batches → outX region (updated in place by k_finalize)
  k_micro_mlp<<<1024, 256, 0, stream>>>(micro, mpw, mpb, outX);

  for (int b0 = 0; b0 < 4; b0 += nb) {
    for (int bi = 0; bi < nb; ++bi) {
      k_gemm256T<<<128, 256, 0, stream>>>(outX + (size_t)(b0 + bi) * 524288, wq,
                                          Qt + (size_t)bi * 524288, 2048);
      k_gemm256T<<<512, 256, 0, stream>>>(macro + (size_t)(b0 + bi) * 2097152, wk,
                                          Kt + (size_t)bi * 2097152, 8192);
    }
    k_scores_topk<<<nb * 128, 256, 0, stream>>>(Qt, Kt, tkv, tki, nb - 1, lgnb);
    k_finalize<<<nb * 2048, 256, 0, stream>>>(macro + (size_t)b0 * 2097152, wv,
                                              tkv, tki, opw, opb, outX, outW, outI, b0);
  }
}